// Round 9
// baseline (26.669 us; speedup 1.0000x reference)
//
#include <hip/hip_runtime.h>

typedef _Float16 h2v __attribute__((ext_vector_type(2)));

#define PI_OVER_4 0.78539816339744830962f

// ---- DPP lane permutes (VALU pipe) ----
#define DPP_XOR1  0xB1    // quad_perm [1,0,3,2]
#define DPP_XOR2  0x4E    // quad_perm [2,3,0,1]
#define DPP_XOR3  0x1B    // quad_perm [3,2,1,0]
#define DPP_XOR7  0x141   // row_half_mirror
#define DPP_XOR15 0x140   // row_mirror

template <int CTRL>
__device__ __forceinline__ float dppf(float v) {
    return __int_as_float(
        __builtin_amdgcn_update_dpp(0, __float_as_int(v), CTRL, 0xF, 0xF, true));
}
template <int CTRL>
__device__ __forceinline__ h2v dpph(h2v v) {
    int i = __builtin_bit_cast(int, v);
    i = __builtin_amdgcn_update_dpp(0, i, CTRL, 0xF, 0xF, true);
    return __builtin_bit_cast(h2v, i);
}
__device__ __forceinline__ float xor4f(float v) { return dppf<DPP_XOR3>(dppf<DPP_XOR7>(v)); }
__device__ __forceinline__ float xor8f(float v) { return dppf<DPP_XOR7>(dppf<DPP_XOR15>(v)); }

// ---- packed fp16 (VOP3P, full-rate) ----
__device__ __forceinline__ h2v pkh_mul(h2v a, h2v b) {
    h2v d; asm("v_pk_mul_f16 %0, %1, %2" : "=v"(d) : "v"(a), "v"(b)); return d;
}
__device__ __forceinline__ h2v pkh_fma(h2v a, h2v b, h2v c) {
    h2v d; asm("v_pk_fma_f16 %0, %1, %2, %3" : "=v"(d) : "v"(a), "v"(b), "v"(c)); return d;
}
__device__ __forceinline__ h2v pkh_mul_bh(h2v a, h2v b) {       // (a.hi,a.hi) * b
    h2v d; asm("v_pk_mul_f16 %0, %1, %2 op_sel:[1,0] op_sel_hi:[1,1]" : "=v"(d) : "v"(a), "v"(b)); return d;
}
__device__ __forceinline__ h2v pkh_fma_bl(h2v a, h2v b, h2v c) { // (a.lo,a.lo)*b + c
    h2v d; asm("v_pk_fma_f16 %0, %1, %2, %3 op_sel:[0,0,0] op_sel_hi:[0,1,1]" : "=v"(d) : "v"(a), "v"(b), "v"(c)); return d;
}
// |z|^2 accumulation with f16 inputs at f32 precision (v_fma_mix_f32)
__device__ __forceinline__ float fmamix_lo(h2v a, float c) {
    float d; asm("v_fma_mix_f32 %0, %1, %1, %2 op_sel_hi:[1,1,0]" : "=v"(d) : "v"(a), "v"(c)); return d;
}
__device__ __forceinline__ float fmamix_hi(h2v a, float c) {
    float d; asm("v_fma_mix_f32 %0, %1, %1, %2 op_sel:[1,1,0] op_sel_hi:[1,1,0]" : "=v"(d) : "v"(a), "v"(c)); return d;
}

__device__ __forceinline__ h2v h2f(float s) {
    _Float16 h = (_Float16)s; h2v r; r.x = h; r.y = h; return r;
}
__device__ __forceinline__ h2v cvth2(float a, float b) {
    return __builtin_bit_cast(h2v, __builtin_amdgcn_cvt_pkrtz(a, b));
}

// 16 lanes/sample. Pre-L1-ring coords t (s = P t); reg r bits (3..0) = (t4..t7).
// Lane bits u (recode): u3=t0, u2=t1, u1=t0^t2, u0=t1^t3.
// Cross-lane gate masks: g0&g7: lane^15 (g7 also r^1); g1: lane^7; g2: lane^3;
// g3: lane^1 & r^8. Reg gates g4,g5,g6: r^12, r^6, r^3.
// Roles: s0=par(u&11)^par(r&15), s1=par(u&12), s2=par(u&6), s3=pv,
// s4..s7 = pv^par(r&{8,12,14,15}); pv=par(u&3).   [verified rounds 5/6/8]
// This round: no bperm distribution — each lane computes all coefficients
// (trans pipe), f16 expansion, low-VGPR for occupancy.
__global__ __launch_bounds__(256, 6) void qsim8_kernel(
        const float* __restrict__ x, const float* __restrict__ w,
        float* __restrict__ out, int nsamples) {
    const int tid = blockIdx.x * blockDim.x + threadIdx.x;
    const int sample = tid >> 4;
    if (sample >= nsamples) return;
    const int L = threadIdx.x & 15;

    // ---- per-sample angles (wave-uniform w via s_loads; x broadcast in L1D) ----
    const float4* xv = reinterpret_cast<const float4*>(x + (size_t)sample * 8);
    const float4 xa = xv[0], xb = xv[1];
    const float xs[8] = {xa.x, xa.y, xa.z, xa.w, xb.x, xb.y, xb.z, xb.w};

    // ---- L2 fused RY angles (fp32 kept for gate-time h2f, as round 8) ----
    float c2f[8], s2f[8];
#pragma unroll
    for (int q = 0; q < 8; ++q) {
        const float h = fmaf(xs[q], PI_OVER_4, 0.5f * w[16 + 2 * q]);
        __sincosf(h, &s2f[q], &c2f[q]);
    }

    // ---- L1 lane factor: qubits 0..3, running product (fp32, no storage) ----
    const int b0 = (L >> 3) & 1;
    const int b1 = (L >> 2) & 1;
    const int b2 = ((L >> 1) ^ (L >> 3)) & 1;
    const int b3 = (L ^ (L >> 2)) & 1;
    float Fr, Fi;
    {
        const int bsel[4] = {b0, b1, b2, b3};
        Fr = 1.0f; Fi = 0.0f;
#pragma unroll
        for (int q = 0; q < 4; ++q) {
            const float hA = fmaf(xs[q], PI_OVER_4, 0.5f * w[2 * q]);
            const float hB = 0.5f * w[2 * q + 1];
            float sh, ch, sz, cz;
            __sincosf(hA, &sh, &ch);
            __sincosf(hB, &sz, &cz);
            const float gr = bsel[q] ? sh * cz : ch * cz;
            const float gi = bsel[q] ? sh * sz : -ch * sz;
            const float tr = Fr * gr - Fi * gi;
            const float ti = Fr * gi + Fi * gr;
            Fr = tr; Fi = ti;
        }
    }

    // ---- expand product state over qubits 4..7, f16, per-stage coeff prep ----
    h2v z[16];
    z[0] = cvth2(Fr, Fi);
#define EXPSTAGE(Q, M_)                                                     \
    {                                                                       \
        const float hA = fmaf(xs[Q], PI_OVER_4, 0.5f * w[2 * (Q)]);         \
        const float hB = 0.5f * w[2 * (Q) + 1];                             \
        float sh, ch, sz, cz;                                               \
        __sincosf(hA, &sh, &ch);                                            \
        __sincosf(hB, &sz, &cz);                                            \
        const float chcz = ch * cz, chsz = ch * sz;                         \
        const float shcz = sh * cz, shsz = sh * sz;                         \
        const h2v e0  = cvth2(chcz, -chsz);                                 \
        const h2v e0f = cvth2(chsz,  chcz);                                 \
        const h2v e1  = cvth2(shcz,  shsz);                                 \
        const h2v e1f = cvth2(-shsz, shcz);                                 \
        _Pragma("unroll")                                                   \
        for (int j = (M_) - 1; j >= 0; --j) {                               \
            const h2v a = z[j];                                             \
            z[2 * j + 1] = pkh_fma_bl(a, e1, pkh_mul_bh(a, e1f));           \
            z[2 * j]     = pkh_fma_bl(a, e0, pkh_mul_bh(a, e0f));           \
        }                                                                   \
    }
    EXPSTAGE(4, 1)
    EXPSTAGE(5, 2)
    EXPSTAGE(6, 4)
    EXPSTAGE(7, 8)
#undef EXPSTAGE

    const int pv = __popc(L & 3) & 1;

    // ---- fused gates 0 & 7 (lane^15; g7 also r^1) — verified round 5/8:
    //   z'[r]   = K1 a + HG b + (±GC) c + (±HB) d
    //   z'[r+1] = HG a + K1 b - (±HB) c - (±GC) d      (± = (-1)^par(r))
    {
        const float c0 = c2f[0], s0 = s2f[0], c7 = c2f[7], s7 = s2f[7];
        const int pu = __popc(L & 11) & 1;
        const float G = pu ? s0 : -s0;
        const float H = pv ? s7 : -s7;
        const h2v K1p = h2f(c7 * c0);
        const h2v HGp = h2f(H * G);
        const h2v GCp = h2f(G * c7), GCn = h2f(-(G * c7));
        const h2v HBp = h2f(H * c0), HBn = h2f(-(H * c0));
#pragma unroll
        for (int r = 0; r < 16; r += 2) {
            const bool ev = (__builtin_popcount(r) & 1) == 0;   // compile-time
            const h2v gc = ev ? GCp : GCn;
            const h2v hb = ev ? HBp : HBn;
            const h2v ngc = ev ? GCn : GCp;
            const h2v nhb = ev ? HBn : HBp;
            const h2v a = z[r], b = z[r + 1];
            const h2v c = dpph<DPP_XOR15>(a);
            const h2v d = dpph<DPP_XOR15>(b);
            h2v za = pkh_fma(b, HGp, pkh_mul(a, K1p));
            h2v zb = pkh_fma(a, HGp, pkh_mul(b, K1p));
            za = pkh_fma(c, gc, za);  za = pkh_fma(d, hb, za);
            zb = pkh_fma(c, nhb, zb); zb = pkh_fma(d, ngc, zb);
            z[r] = za; z[r + 1] = zb;
        }
    }
    // ---- gate 1: lane^7; role par(u&12) ----
    {
        const h2v ccp = h2f(c2f[1]);
        const h2v gp = h2f((__popc(L & 12) & 1) ? s2f[1] : -s2f[1]);
#pragma unroll
        for (int r = 0; r < 16; ++r) {
            const h2v o = dpph<DPP_XOR7>(z[r]);
            z[r] = pkh_fma(o, gp, pkh_mul(z[r], ccp));
        }
    }
    // ---- gate 2: lane^3; role par(u&6) ----
    {
        const h2v ccp = h2f(c2f[2]);
        const h2v gp = h2f((__popc(L & 6) & 1) ? s2f[2] : -s2f[2]);
#pragma unroll
        for (int r = 0; r < 16; ++r) {
            const h2v o = dpph<DPP_XOR3>(z[r]);
            z[r] = pkh_fma(o, gp, pkh_mul(z[r], ccp));
        }
    }
    // ---- gate 3: lane^1 & r^8; role pv ----
    {
        const h2v ccp = h2f(c2f[3]);
        const h2v gp = h2f(pv ? s2f[3] : -s2f[3]);
#pragma unroll
        for (int r = 0; r < 8; ++r) {
            const h2v oA = dpph<DPP_XOR1>(z[r + 8]);
            const h2v oB = dpph<DPP_XOR1>(z[r]);
            z[r]     = pkh_fma(oA, gp, pkh_mul(z[r], ccp));
            z[r + 8] = pkh_fma(oB, gp, pkh_mul(z[r + 8], ccp));
        }
    }
    // ---- reg-local gates 4..6: pair r^MR; role pv ^ par(r&RR) ----
#define REGGATE(Q, MR, HBIT, RR)                                              \
    {                                                                         \
        const float gbase = pv ? s2f[Q] : -s2f[Q];                            \
        const h2v ccp = h2f(c2f[Q]);                                          \
        const h2v gp = h2f(gbase), gn = h2f(-gbase);                          \
        _Pragma("unroll")                                                     \
        for (int r = 0; r < 16; ++r) {                                        \
            if ((r & (HBIT)) == 0) {                                          \
                const int rB = r ^ (MR);                                      \
                const bool pos = (__builtin_popcount(r & (RR)) & 1) == 0;     \
                const h2v s1 = pos ? gp : gn;                                 \
                const h2v s2 = pos ? gn : gp;                                 \
                const h2v a = z[r], b = z[rB];                                \
                z[r]  = pkh_fma(b, s1, pkh_mul(a, ccp));                      \
                z[rB] = pkh_fma(a, s2, pkh_mul(b, ccp));                      \
            }                                                                 \
        }                                                                     \
    }
    REGGATE(4, 12, 8, 8)
    REGGATE(5, 6, 4, 12)
    REGGATE(6, 3, 2, 14)
#undef REGGATE

    // ---- probabilities: f16 inputs, f32 multiply+accumulate (v_fma_mix) ----
    float p[16];
#pragma unroll
    for (int r = 0; r < 16; ++r)
        p[r] = fmamix_hi(z[r], fmamix_lo(z[r], 0.0f));

    // ---- 5 masked register sums S_m, m in {5,7,10,11,15} (fp32 shared trees) ----
    float P[8], M[8];
#pragma unroll
    for (int j = 0; j < 8; ++j) {
        P[j] = p[2 * j] + p[2 * j + 1];
        M[j] = p[2 * j] - p[2 * j + 1];
    }
    float MP[4], MM[4], PM[4];
#pragma unroll
    for (int i = 0; i < 4; ++i) {
        MP[i] = M[2 * i] + M[2 * i + 1];
        MM[i] = M[2 * i] - M[2 * i + 1];
        PM[i] = P[2 * i] - P[2 * i + 1];
    }
    const float MPM0 = MP[0] - MP[1], MPM1 = MP[2] - MP[3];
    const float MMM0 = MM[0] - MM[1], MMM1 = MM[2] - MM[3];
    const float MMP0 = MM[0] + MM[1], MMP1 = MM[2] + MM[3];
    const float PMP0 = PM[0] + PM[1], PMP1 = PM[2] + PM[3];
    const float S5  = MPM0 + MPM1;
    const float S7  = MMM0 + MMM1;
    const float S15 = MMM0 - MMM1;
    const float S11 = MMP0 - MMP1;
    const float S10 = PMP0 - PMP1;

    // ---- lane sign prefactors; C_i lane masks: {9,7,1,2,1,2,1,2} ----
    const float sg1 = (L & 1) ? -1.f : 1.f;
    const float sg2 = (L & 2) ? -1.f : 1.f;
    const float sg9 = (__popc(L & 9) & 1) ? -1.f : 1.f;
    const float sg7 = (__popc(L & 7) & 1) ? -1.f : 1.f;
    float acc[8];
    acc[0] = sg9 * S5;
    acc[1] = sg7 * S15;
    acc[2] = sg1 * S15;
    acc[3] = sg2 * S15;
    acc[4] = sg1 * S7;
    acc[5] = sg2 * S11;
    acc[6] = sg1 * S5;
    acc[7] = sg2 * S10;

    // ---- transpose-reduce over 16 lanes (DPP); lane L<8 ends with sum of acc[L] ----
    const int h0 = L & 1, h1 = (L >> 1) & 1, h2 = (L >> 2) & 1;
    float t4a[4];
#pragma unroll
    for (int k = 0; k < 4; ++k) {
        const float send = h0 ? acc[2 * k] : acc[2 * k + 1];
        const float recv = dppf<DPP_XOR1>(send);
        t4a[k] = (h0 ? acc[2 * k + 1] : acc[2 * k]) + recv;
    }
    float t2a[2];
#pragma unroll
    for (int k = 0; k < 2; ++k) {
        const float send = h1 ? t4a[2 * k] : t4a[2 * k + 1];
        const float recv = dppf<DPP_XOR2>(send);
        t2a[k] = (h1 ? t4a[2 * k + 1] : t4a[2 * k]) + recv;
    }
    {
        const float send = h2 ? t2a[0] : t2a[1];
        const float recv = xor4f(send);
        float res = (h2 ? t2a[1] : t2a[0]) + recv;
        res += xor8f(res);   // fold the two u3-halves
        if (L < 8) out[(size_t)sample * 8 + L] = res;
    }
}

extern "C" void kernel_launch(void* const* d_in, const int* in_sizes, int n_in,
                              void* d_out, int out_size, void* d_ws, size_t ws_size,
                              hipStream_t stream) {
    const float* x = (const float*)d_in[0];
    const float* w = (const float*)d_in[1];
    float* outp = (float*)d_out;
    const int nsamples = in_sizes[0] / 8;
    const int nthreads = nsamples * 16;
    const int block = 256;
    const int grid = (nthreads + block - 1) / block;
    qsim8_kernel<<<grid, block, 0, stream>>>(x, w, outp, nsamples);
}

// Round 10
// 20.108 us; speedup vs baseline: 1.3263x; 1.3263x over previous
//
#include <hip/hip_runtime.h>

typedef _Float16 h2v __attribute__((ext_vector_type(2)));

#define PI_OVER_4 0.78539816339744830962f

// ---- DPP lane permutes (VALU pipe) ----
#define DPP_XOR1  0xB1    // quad_perm [1,0,3,2]
#define DPP_XOR2  0x4E    // quad_perm [2,3,0,1]
#define DPP_XOR3  0x1B    // quad_perm [3,2,1,0]
#define DPP_XOR7  0x141   // row_half_mirror

template <int CTRL>
__device__ __forceinline__ float dppf(float v) {
    return __int_as_float(
        __builtin_amdgcn_update_dpp(0, __float_as_int(v), CTRL, 0xF, 0xF, true));
}
template <int CTRL>
__device__ __forceinline__ h2v dpph(h2v v) {
    int i = __builtin_bit_cast(int, v);
    i = __builtin_amdgcn_update_dpp(0, i, CTRL, 0xF, 0xF, true);
    return __builtin_bit_cast(h2v, i);
}
__device__ __forceinline__ float xor4f(float v) { return dppf<DPP_XOR3>(dppf<DPP_XOR7>(v)); }

// ---- packed fp16 VOP3P with op_sel splats (coefficient in src0) ----
__device__ __forceinline__ h2v pkh_mul_lo(h2v a, h2v b) {   // (a.lo,a.lo)*b
    h2v d; asm("v_pk_mul_f16 %0, %1, %2 op_sel:[0,0] op_sel_hi:[0,1]" : "=v"(d) : "v"(a), "v"(b)); return d;
}
__device__ __forceinline__ h2v pkh_mul_hi(h2v a, h2v b) {   // (a.hi,a.hi)*b
    h2v d; asm("v_pk_mul_f16 %0, %1, %2 op_sel:[1,0] op_sel_hi:[1,1]" : "=v"(d) : "v"(a), "v"(b)); return d;
}
__device__ __forceinline__ h2v pkh_fma_lo(h2v a, h2v b, h2v c) { // (a.lo,a.lo)*b + c
    h2v d; asm("v_pk_fma_f16 %0, %1, %2, %3 op_sel:[0,0,0] op_sel_hi:[0,1,1]" : "=v"(d) : "v"(a), "v"(b), "v"(c)); return d;
}
__device__ __forceinline__ h2v pkh_fma_hi(h2v a, h2v b, h2v c) { // (a.hi,a.hi)*b + c
    h2v d; asm("v_pk_fma_f16 %0, %1, %2, %3 op_sel:[1,0,0] op_sel_hi:[1,1,1]" : "=v"(d) : "v"(a), "v"(b), "v"(c)); return d;
}
__device__ __forceinline__ h2v pkh_mul(h2v a, h2v b) {      // elementwise
    h2v d; asm("v_pk_mul_f16 %0, %1, %2" : "=v"(d) : "v"(a), "v"(b)); return d;
}
__device__ __forceinline__ h2v pkh_mul_x(h2v a, h2v b) {    // (a.hi*b.lo, a.lo*b.hi)
    h2v d; asm("v_pk_mul_f16 %0, %1, %2 op_sel:[1,0] op_sel_hi:[0,1]" : "=v"(d) : "v"(a), "v"(b)); return d;
}
// |z|^2 at f32 precision from f16 halves
__device__ __forceinline__ float fmamix_lo(h2v a, float c) {
    float d; asm("v_fma_mix_f32 %0, %1, %1, %2 op_sel_hi:[1,1,0]" : "=v"(d) : "v"(a), "v"(c)); return d;
}
__device__ __forceinline__ float fmamix_hi(h2v a, float c) {
    float d; asm("v_fma_mix_f32 %0, %1, %1, %2 op_sel:[1,1,0] op_sel_hi:[1,1,0]" : "=v"(d) : "v"(a), "v"(c)); return d;
}

__device__ __forceinline__ h2v hxor(h2v a, unsigned m) {
    return __builtin_bit_cast(h2v, __builtin_bit_cast(unsigned, a) ^ m);
}
__device__ __forceinline__ h2v cvth2(float a, float b) {
    return __builtin_bit_cast(h2v, __builtin_amdgcn_cvt_pkrtz(a, b));
}
__device__ __forceinline__ float bperm(int addr, float v) {
    return __int_as_float(__builtin_amdgcn_ds_bpermute(addr, __float_as_int(v)));
}
__device__ __forceinline__ h2v bpermh(int addr, h2v v) {
    return __builtin_bit_cast(h2v,
        __builtin_amdgcn_ds_bpermute(addr, __builtin_bit_cast(int, v)));
}

// 8 lanes/sample (round-3-verified geometry). Pre-L1-ring coords t; reg r bits
// (4..0) = (t3..t7). Lane recode: u2=t0, u1=t1, u0=t1^t2.
// Gates: g0&7: lane^7 (g7 also r^1); g1: lane^2; g2: lane^1 & r^16;
// g3..g6 reg-local: r^{24,12,6,3}. Roles: pu=L&1 (g0), pl=par(L&5) (g2..g7),
// p01=par(L&6) (g1). Epilogue masks verified in round 3.
// Coefficients: lane q computes 3 sincos for qubit q; packed distribution via
// 40 ds_bpermute; gate coefficient = one (c,s) h2v, role sign via u32 XOR,
// lo/hi op_sel splats in the pk ops.
__global__ __launch_bounds__(256, 4) void qsim8_kernel(
        const float* __restrict__ x, const float* __restrict__ w,
        float* __restrict__ out, int nsamples) {
    const int tid = blockIdx.x * blockDim.x + threadIdx.x;
    const int sample = tid >> 3;
    if (sample >= nsamples) return;
    const int lane = threadIdx.x & 63;
    const int L = lane & 7;

    // ---- per-lane transcendentals: qubit q = L (3 sincos) ----
    const float xq = x[(size_t)sample * 8 + L];
    const float wA = w[2 * L], wB = w[2 * L + 1], w2 = w[16 + 2 * L];
    float sh, ch, sz, cz, s2v, c2v;
    __sincosf(fmaf(xq, PI_OVER_4, 0.5f * wA), &sh, &ch);
    __sincosf(0.5f * wB, &sz, &cz);
    __sincosf(fmaf(xq, PI_OVER_4, 0.5f * w2), &s2v, &c2v);
    const float v_chcz = ch * cz, v_chsz = ch * sz;
    const float v_shcz = sh * cz, v_shsz = sh * sz;
    // packed sends
    const h2v se0  = cvth2(v_chcz, -v_chsz);
    const h2v se0f = cvth2(v_chsz,  v_chcz);
    const h2v se1  = cvth2(v_shcz,  v_shsz);
    const h2v se1f = cvth2(-v_shsz, v_shcz);
    const h2v scs  = cvth2(c2v, s2v);

    // ---- distribute within the 8-lane group (40 bperms) ----
    const int base = (lane & 56) << 2;
    float lf_chcz[3], lf_chsz[3], lf_shcz[3], lf_shsz[3];
#pragma unroll
    for (int q = 0; q < 3; ++q) {
        const int ad = base + 4 * q;
        lf_chcz[q] = bperm(ad, v_chcz); lf_chsz[q] = bperm(ad, v_chsz);
        lf_shcz[q] = bperm(ad, v_shcz); lf_shsz[q] = bperm(ad, v_shsz);
    }
    h2v ex_e0[5], ex_e0f[5], ex_e1[5], ex_e1f[5];
#pragma unroll
    for (int k = 0; k < 5; ++k) {
        const int ad = base + 4 * (3 + k);
        ex_e0[k] = bpermh(ad, se0);   ex_e0f[k] = bpermh(ad, se0f);
        ex_e1[k] = bpermh(ad, se1);   ex_e1f[k] = bpermh(ad, se1f);
    }
    h2v cs[8];
#pragma unroll
    for (int q = 0; q < 8; ++q) cs[q] = bpermh(base + 4 * q, scs);

    // ---- lane factor: qubits 0..2 selected by round-3 bits ----
    const int b0 = (L >> 2) & 1;
    const int b1 = (L >> 1) & 1;
    const int b2 = ((L >> 1) ^ L) & 1;
    float Fr = b0 ? lf_shcz[0] : lf_chcz[0];
    float Fi = b0 ? lf_shsz[0] : -lf_chsz[0];
    {
        const float g1r = b1 ? lf_shcz[1] : lf_chcz[1];
        const float g1i = b1 ? lf_shsz[1] : -lf_chsz[1];
        const float tr = Fr * g1r - Fi * g1i;
        const float ti = Fr * g1i + Fi * g1r;
        const float g2r = b2 ? lf_shcz[2] : lf_chcz[2];
        const float g2i = b2 ? lf_shsz[2] : -lf_chsz[2];
        Fr = tr * g2r - ti * g2i;
        Fi = tr * g2i + ti * g2r;
    }

    // ---- expand product state over qubits 3..7 (f16; r bit4=t3 .. bit0=t7) ----
    h2v z[32];
    z[0] = cvth2(Fr, Fi);
#define EXPAND(K, M_)                                                       \
    {                                                                       \
        const h2v e0 = ex_e0[K], e0f = ex_e0f[K];                           \
        const h2v e1 = ex_e1[K], e1f = ex_e1f[K];                           \
        _Pragma("unroll")                                                   \
        for (int j = (M_) - 1; j >= 0; --j) {                               \
            const h2v a = z[j];                                             \
            z[2 * j + 1] = pkh_fma_lo(a, e1, pkh_mul_hi(a, e1f));           \
            z[2 * j]     = pkh_fma_lo(a, e0, pkh_mul_hi(a, e0f));           \
        }                                                                   \
    }
    EXPAND(0, 1)
    EXPAND(1, 2)
    EXPAND(2, 4)
    EXPAND(3, 8)
    EXPAND(4, 16)
#undef EXPAND

    const int pu = L & 1;                 // p12: role of g0
    const int pl = __popc(L & 5) & 1;     // role of g2..g7
    const int p01 = __popc(L & 6) & 1;    // role of g1

    // ---- fused gates 0 & 7 (lane^7; g7 also r^1) — round-3-verified algebra:
    //   z'[r]   = K1 a + HG b + gc c + hb d
    //   z'[r+1] = HG a + K1 b - hb c - gc d   (gc,hb sign-flip on odd par(r))
    {
        h2v K1HG = pkh_mul(cs[0], cs[7]);            // (c0c7, s0s7)
        K1HG = hxor(K1HG, (pu ^ pl) ? 0x80000000u : 0u);
        h2v GE = pkh_mul_x(cs[0], cs[7]);            // (s0c7, c0s7)
        GE = hxor(GE, (pu ? 0u : 0x8000u) | (pl ? 0u : 0x80000000u));
        const h2v GO = hxor(GE, 0x80008000u);
#pragma unroll
        for (int r = 0; r < 32; r += 2) {
            const bool ev = (__builtin_popcount(r) & 1) == 0;   // compile-time
            const h2v GA = ev ? GE : GO;
            const h2v GB = ev ? GO : GE;
            const h2v a = z[r], b = z[r + 1];
            const h2v c = dpph<DPP_XOR7>(a);
            const h2v d = dpph<DPP_XOR7>(b);
            h2v za = pkh_fma_hi(K1HG, b, pkh_mul_lo(K1HG, a));
            za = pkh_fma_lo(GA, c, za);
            za = pkh_fma_hi(GA, d, za);
            h2v zb = pkh_fma_lo(K1HG, b, pkh_mul_hi(K1HG, a));
            zb = pkh_fma_hi(GB, c, zb);
            zb = pkh_fma_lo(GB, d, zb);
            z[r] = za; z[r + 1] = zb;
        }
    }
    // ---- gate 1: lane^2; role p01 ----
    {
        const h2v cg = hxor(cs[1], p01 ? 0u : 0x80000000u);
#pragma unroll
        for (int r = 0; r < 32; ++r) {
            const h2v o = dpph<DPP_XOR2>(z[r]);
            z[r] = pkh_fma_hi(cg, o, pkh_mul_lo(cg, z[r]));
        }
    }
    // ---- gate 2: lane^1 & r^16; role pl ----
    {
        const h2v cg = hxor(cs[2], pl ? 0u : 0x80000000u);
#pragma unroll
        for (int r = 0; r < 16; ++r) {
            const h2v oA = dpph<DPP_XOR1>(z[r + 16]);
            const h2v oB = dpph<DPP_XOR1>(z[r]);
            z[r]      = pkh_fma_hi(cg, oA, pkh_mul_lo(cg, z[r]));
            z[r + 16] = pkh_fma_hi(cg, oB, pkh_mul_lo(cg, z[r + 16]));
        }
    }
    // ---- reg-local gates 3..6: pair r^MR; sign = pl ^ par(r&RR) ----
#define REGGATE(Q, MR, HBIT, RR)                                              \
    {                                                                         \
        const h2v CP = hxor(cs[Q], pl ? 0u : 0x80000000u);                    \
        const h2v CN = hxor(CP, 0x80000000u);                                 \
        _Pragma("unroll")                                                     \
        for (int r = 0; r < 32; ++r) {                                        \
            if ((r & (HBIT)) == 0) {                                          \
                const int rB = r ^ (MR);                                      \
                const bool pos = (__builtin_popcount(r & (RR)) & 1) == 0;     \
                const h2v a = z[r], b = z[rB];                                \
                z[r]  = pkh_fma_hi(pos ? CP : CN, b, pkh_mul_lo(CP, a));      \
                z[rB] = pkh_fma_hi(pos ? CN : CP, a, pkh_mul_lo(CP, b));      \
            }                                                                 \
        }                                                                     \
    }
    REGGATE(3, 24, 16, 16)
    REGGATE(4, 12, 8, 24)
    REGGATE(5, 6, 4, 28)
    REGGATE(6, 3, 2, 30)
#undef REGGATE

    // ---- probabilities (f32 via fma_mix) folded into uu/vv ----
    float uu[16], vv[16];
#pragma unroll
    for (int k = 0; k < 16; ++k) {
        const float pa = fmamix_hi(z[k], fmamix_lo(z[k], 0.0f));
        const float pb = fmamix_hi(z[k + 16], fmamix_lo(z[k + 16], 0.0f));
        uu[k] = pa + pb;
        vv[k] = pa - pb;
    }
    // ---- round-3-verified shared trees ----
    float Pu[8], Mu[8], Mv[8];
#pragma unroll
    for (int j = 0; j < 8; ++j) {
        Pu[j] = uu[2 * j] + uu[2 * j + 1];
        Mu[j] = uu[2 * j] - uu[2 * j + 1];
        Mv[j] = vv[2 * j] - vv[2 * j + 1];
    }
    float PA[4], MB[4], Pv[4], Qv[4];
#pragma unroll
    for (int i = 0; i < 4; ++i) {
        PA[i] = Pu[2 * i] - Pu[2 * i + 1];
        MB[i] = Mu[2 * i] - Mu[2 * i + 1];
        Pv[i] = Mv[2 * i] + Mv[2 * i + 1];
        Qv[i] = Mv[2 * i] - Mv[2 * i + 1];
    }
    const float QA0 = PA[0] + PA[1], QA1 = PA[2] + PA[3];
    const float QB0 = MB[0] + MB[1], QB1 = MB[2] + MB[3];
    const float QF0 = MB[0] - MB[1], QF1 = MB[2] - MB[3];
    const float Pp0 = Pv[0] - Pv[1], Pp1 = Pv[2] - Pv[3];
    const float Qp0 = Qv[0] - Qv[1], Qp1 = Qv[2] - Qv[3];
    const float s0A = QA0 - QA1;
    const float s0B = QB0 - QB1;
    const float s0F = QF0 - QF1;
    const float s15 = Pp0 + Pp1;
    const float s17 = Qp0 + Qp1;
    const float s1F = Qp0 - Qp1;

    const float A  = p01 ? -1.f : 1.f;
    const float Bs = (__popc(L & 7) & 1) ? -1.f : 1.f;
    const float D  = (L & 2) ? -1.f : 1.f;
    float acc[8];
    acc[0] = A * s15;
    acc[1] = Bs * s1F;
    acc[2] = D * s1F;
    acc[3] = Bs * s0F;
    acc[4] = D * s17;
    acc[5] = Bs * s0B;
    acc[6] = D * s15;
    acc[7] = Bs * s0A;

    // ---- transpose-reduce over 8 lanes (DPP); lane L ends with sum of acc[L] ----
    const int h0 = L & 1, h1 = (L >> 1) & 1, h2 = (L >> 2) & 1;
    float t4a[4];
#pragma unroll
    for (int k = 0; k < 4; ++k) {
        const float send = h0 ? acc[2 * k] : acc[2 * k + 1];
        const float recv = dppf<DPP_XOR1>(send);
        t4a[k] = (h0 ? acc[2 * k + 1] : acc[2 * k]) + recv;
    }
    float t2a[2];
#pragma unroll
    for (int k = 0; k < 2; ++k) {
        const float send = h1 ? t4a[2 * k] : t4a[2 * k + 1];
        const float recv = dppf<DPP_XOR2>(send);
        t2a[k] = (h1 ? t4a[2 * k + 1] : t4a[2 * k]) + recv;
    }
    {
        const float send = h2 ? t2a[0] : t2a[1];
        const float recv = xor4f(send);
        const float res = (h2 ? t2a[1] : t2a[0]) + recv;
        out[(size_t)sample * 8 + L] = res;
    }
}

extern "C" void kernel_launch(void* const* d_in, const int* in_sizes, int n_in,
                              void* d_out, int out_size, void* d_ws, size_t ws_size,
                              hipStream_t stream) {
    const float* x = (const float*)d_in[0];
    const float* w = (const float*)d_in[1];
    float* outp = (float*)d_out;
    const int nsamples = in_sizes[0] / 8;
    const int nthreads = nsamples * 8;
    const int block = 256;
    const int grid = (nthreads + block - 1) / block;
    qsim8_kernel<<<grid, block, 0, stream>>>(x, w, outp, nsamples);
}

// Round 11
// 19.856 us; speedup vs baseline: 1.3431x; 1.0127x over previous
//
#include <hip/hip_runtime.h>

typedef _Float16 h2v __attribute__((ext_vector_type(2)));
typedef __fp16 hf2 __attribute__((ext_vector_type(2)));

#define PI_OVER_4 0.78539816339744830962f

// ---- DPP lane permutes (VALU pipe) ----
#define DPP_XOR1  0xB1    // quad_perm [1,0,3,2]
#define DPP_XOR2  0x4E    // quad_perm [2,3,0,1]
#define DPP_XOR3  0x1B    // quad_perm [3,2,1,0]
#define DPP_XOR7  0x141   // row_half_mirror

template <int CTRL>
__device__ __forceinline__ float dppf(float v) {
    return __int_as_float(
        __builtin_amdgcn_update_dpp(0, __float_as_int(v), CTRL, 0xF, 0xF, true));
}
template <int CTRL>
__device__ __forceinline__ h2v dpph(h2v v) {
    int i = __builtin_bit_cast(int, v);
    i = __builtin_amdgcn_update_dpp(0, i, CTRL, 0xF, 0xF, true);
    return __builtin_bit_cast(h2v, i);
}
__device__ __forceinline__ float xor4f(float v) { return dppf<DPP_XOR3>(dppf<DPP_XOR7>(v)); }

// ---- packed fp16 VOP3P with op_sel splats (coefficient in src0) ----
__device__ __forceinline__ h2v pkh_mul_lo(h2v a, h2v b) {   // (a.lo,a.lo)*b
    h2v d; asm("v_pk_mul_f16 %0, %1, %2 op_sel:[0,0] op_sel_hi:[0,1]" : "=v"(d) : "v"(a), "v"(b)); return d;
}
__device__ __forceinline__ h2v pkh_mul_hi(h2v a, h2v b) {   // (a.hi,a.hi)*b
    h2v d; asm("v_pk_mul_f16 %0, %1, %2 op_sel:[1,0] op_sel_hi:[1,1]" : "=v"(d) : "v"(a), "v"(b)); return d;
}
__device__ __forceinline__ h2v pkh_fma_lo(h2v a, h2v b, h2v c) { // (a.lo,a.lo)*b + c
    h2v d; asm("v_pk_fma_f16 %0, %1, %2, %3 op_sel:[0,0,0] op_sel_hi:[0,1,1]" : "=v"(d) : "v"(a), "v"(b), "v"(c)); return d;
}
__device__ __forceinline__ h2v pkh_fma_hi(h2v a, h2v b, h2v c) { // (a.hi,a.hi)*b + c
    h2v d; asm("v_pk_fma_f16 %0, %1, %2, %3 op_sel:[1,0,0] op_sel_hi:[1,1,1]" : "=v"(d) : "v"(a), "v"(b), "v"(c)); return d;
}
__device__ __forceinline__ h2v pkh_mul(h2v a, h2v b) {      // elementwise
    h2v d; asm("v_pk_mul_f16 %0, %1, %2" : "=v"(d) : "v"(a), "v"(b)); return d;
}
__device__ __forceinline__ h2v pkh_mul_x(h2v a, h2v b) {    // (a.hi*b.lo, a.lo*b.hi)
    h2v d; asm("v_pk_mul_f16 %0, %1, %2 op_sel:[1,0] op_sel_hi:[0,1]" : "=v"(d) : "v"(a), "v"(b)); return d;
}
// (a.hi * -e.hi, a.hi * e.lo): turns e=(c,-s) into the swapped factor (s,c),
// and e=(c2,s2) into (-s2,c2) — replaces the separate e0f/e1f coefficients.
__device__ __forceinline__ h2v pkh_mul_hs(h2v a, h2v e) {
    h2v d; asm("v_pk_mul_f16 %0, %1, %2 op_sel:[1,1] op_sel_hi:[1,0] neg_lo:[0,1] neg_hi:[0,0]"
               : "=v"(d) : "v"(a), "v"(e)); return d;
}
// |z|^2 with f32 accumulate: z.lo*z.lo + z.hi*z.hi + c
__device__ __forceinline__ float dot2(h2v a, float c) {
    return __builtin_amdgcn_fdot2(__builtin_bit_cast(hf2, a), __builtin_bit_cast(hf2, a), c, false);
}

__device__ __forceinline__ h2v hxor(h2v a, unsigned m) {
    return __builtin_bit_cast(h2v, __builtin_bit_cast(unsigned, a) ^ m);
}
__device__ __forceinline__ h2v cvth2(float a, float b) {
    return __builtin_bit_cast(h2v, __builtin_amdgcn_cvt_pkrtz(a, b));
}
__device__ __forceinline__ float bperm(int addr, float v) {
    return __int_as_float(__builtin_amdgcn_ds_bpermute(addr, __float_as_int(v)));
}
__device__ __forceinline__ h2v bpermh(int addr, h2v v) {
    return __builtin_bit_cast(h2v,
        __builtin_amdgcn_ds_bpermute(addr, __builtin_bit_cast(int, v)));
}

// 8 lanes/sample (round-3/10-verified geometry). Pre-L1-ring coords t; reg r
// bits (4..0) = (t3..t7). Lane recode: u2=t0, u1=t1, u0=t1^t2.
// Gates: g0&7: lane^7 (g7 also r^1); g1: lane^2; g2: lane^1 & r^16;
// g3..g6 reg-local: r^{24,12,6,3}. Roles: pu=L&1 (g0), pl=par(L&5) (g2..g7),
// p01=par(L&6) (g1). Epilogue masks verified round 3/10.
// This round: dot2 probabilities, op_sel-folded expand coefficients (30
// bperms), launch_bounds(256,8) targeting 64 VGPR = full-grid residency.
__global__ __launch_bounds__(256, 8) void qsim8_kernel(
        const float* __restrict__ x, const float* __restrict__ w,
        float* __restrict__ out, int nsamples) {
    const int tid = blockIdx.x * blockDim.x + threadIdx.x;
    const int sample = tid >> 3;
    if (sample >= nsamples) return;
    const int lane = threadIdx.x & 63;
    const int L = lane & 7;

    // ---- per-lane transcendentals: qubit q = L (3 sincos) ----
    const float xq = x[(size_t)sample * 8 + L];
    const float wA = w[2 * L], wB = w[2 * L + 1], w2 = w[16 + 2 * L];
    float sh, ch, sz, cz, s2v, c2v;
    __sincosf(fmaf(xq, PI_OVER_4, 0.5f * wA), &sh, &ch);
    __sincosf(0.5f * wB, &sz, &cz);
    __sincosf(fmaf(xq, PI_OVER_4, 0.5f * w2), &s2v, &c2v);
    const float v_chcz = ch * cz, v_chsz = ch * sz;
    const float v_shcz = sh * cz, v_shsz = sh * sz;
    // packed sends: e0=(chcz,-chsz), e1=(shcz,shsz), cs=(c2,s2)
    const h2v se0 = cvth2(v_chcz, -v_chsz);
    const h2v se1 = cvth2(v_shcz,  v_shsz);
    const h2v scs = cvth2(c2v, s2v);

    // ---- distribute within the 8-lane group (30 bperms) ----
    const int base = (lane & 56) << 2;
    float lf_chcz[3], lf_chsz[3], lf_shcz[3], lf_shsz[3];
#pragma unroll
    for (int q = 0; q < 3; ++q) {
        const int ad = base + 4 * q;
        lf_chcz[q] = bperm(ad, v_chcz); lf_chsz[q] = bperm(ad, v_chsz);
        lf_shcz[q] = bperm(ad, v_shcz); lf_shsz[q] = bperm(ad, v_shsz);
    }
    h2v ex_e0[5], ex_e1[5];
#pragma unroll
    for (int k = 0; k < 5; ++k) {
        const int ad = base + 4 * (3 + k);
        ex_e0[k] = bpermh(ad, se0);
        ex_e1[k] = bpermh(ad, se1);
    }
    h2v cs[8];
#pragma unroll
    for (int q = 0; q < 8; ++q) cs[q] = bpermh(base + 4 * q, scs);

    // ---- lane factor: qubits 0..2 selected by round-3 bits (fp32) ----
    const int b0 = (L >> 2) & 1;
    const int b1 = (L >> 1) & 1;
    const int b2 = ((L >> 1) ^ L) & 1;
    float Fr = b0 ? lf_shcz[0] : lf_chcz[0];
    float Fi = b0 ? lf_shsz[0] : -lf_chsz[0];
    {
        const float g1r = b1 ? lf_shcz[1] : lf_chcz[1];
        const float g1i = b1 ? lf_shsz[1] : -lf_chsz[1];
        const float tr = Fr * g1r - Fi * g1i;
        const float ti = Fr * g1i + Fi * g1r;
        const float g2r = b2 ? lf_shcz[2] : lf_chcz[2];
        const float g2i = b2 ? lf_shsz[2] : -lf_chsz[2];
        Fr = tr * g2r - ti * g2i;
        Fi = tr * g2i + ti * g2r;
    }

    // ---- expand product state over qubits 3..7 (f16; r bit4=t3 .. bit0=t7)
    //  z*f1 = fma_lo(a,e1) + mul_hs(a,e1):  (a.lo*shcz - a.hi*shsz, a.lo*shsz + a.hi*shcz)
    //  z*f0 = fma_lo(a,e0) + mul_hs(a,e0):  (a.lo*chcz + a.hi*chsz, a.lo*(-chsz) + a.hi*chcz)
    h2v z[32];
    z[0] = cvth2(Fr, Fi);
#define EXPAND(K, M_)                                                       \
    {                                                                       \
        const h2v e0 = ex_e0[K], e1 = ex_e1[K];                             \
        _Pragma("unroll")                                                   \
        for (int j = (M_) - 1; j >= 0; --j) {                               \
            const h2v a = z[j];                                             \
            z[2 * j + 1] = pkh_fma_lo(a, e1, pkh_mul_hs(a, e1));            \
            z[2 * j]     = pkh_fma_lo(a, e0, pkh_mul_hs(a, e0));            \
        }                                                                   \
    }
    EXPAND(0, 1)
    EXPAND(1, 2)
    EXPAND(2, 4)
    EXPAND(3, 8)
    EXPAND(4, 16)
#undef EXPAND

    const int pu = L & 1;                 // p12: role of g0
    const int pl = __popc(L & 5) & 1;     // role of g2..g7
    const int p01 = __popc(L & 6) & 1;    // role of g1

    // ---- fused gates 0 & 7 (lane^7; g7 also r^1) — round-3/10-verified ----
    {
        h2v K1HG = pkh_mul(cs[0], cs[7]);            // (c0c7, s0s7)
        K1HG = hxor(K1HG, (pu ^ pl) ? 0x80000000u : 0u);
        h2v GE = pkh_mul_x(cs[0], cs[7]);            // (s0c7, c0s7)
        GE = hxor(GE, (pu ? 0u : 0x8000u) | (pl ? 0u : 0x80000000u));
        const h2v GO = hxor(GE, 0x80008000u);
#pragma unroll
        for (int r = 0; r < 32; r += 2) {
            const bool ev = (__builtin_popcount(r) & 1) == 0;   // compile-time
            const h2v GA = ev ? GE : GO;
            const h2v GB = ev ? GO : GE;
            const h2v a = z[r], b = z[r + 1];
            const h2v c = dpph<DPP_XOR7>(a);
            const h2v d = dpph<DPP_XOR7>(b);
            h2v za = pkh_fma_hi(K1HG, b, pkh_mul_lo(K1HG, a));
            za = pkh_fma_lo(GA, c, za);
            za = pkh_fma_hi(GA, d, za);
            h2v zb = pkh_fma_lo(K1HG, b, pkh_mul_hi(K1HG, a));
            zb = pkh_fma_hi(GB, c, zb);
            zb = pkh_fma_lo(GB, d, zb);
            z[r] = za; z[r + 1] = zb;
        }
    }
    // ---- gate 1: lane^2; role p01 ----
    {
        const h2v cg = hxor(cs[1], p01 ? 0u : 0x80000000u);
#pragma unroll
        for (int r = 0; r < 32; ++r) {
            const h2v o = dpph<DPP_XOR2>(z[r]);
            z[r] = pkh_fma_hi(cg, o, pkh_mul_lo(cg, z[r]));
        }
    }
    // ---- gate 2: lane^1 & r^16; role pl ----
    {
        const h2v cg = hxor(cs[2], pl ? 0u : 0x80000000u);
#pragma unroll
        for (int r = 0; r < 16; ++r) {
            const h2v oA = dpph<DPP_XOR1>(z[r + 16]);
            const h2v oB = dpph<DPP_XOR1>(z[r]);
            z[r]      = pkh_fma_hi(cg, oA, pkh_mul_lo(cg, z[r]));
            z[r + 16] = pkh_fma_hi(cg, oB, pkh_mul_lo(cg, z[r + 16]));
        }
    }
    // ---- reg-local gates 3..6: pair r^MR; sign = pl ^ par(r&RR) ----
#define REGGATE(Q, MR, HBIT, RR)                                              \
    {                                                                         \
        const h2v CP = hxor(cs[Q], pl ? 0u : 0x80000000u);                    \
        const h2v CN = hxor(CP, 0x80000000u);                                 \
        _Pragma("unroll")                                                     \
        for (int r = 0; r < 32; ++r) {                                        \
            if ((r & (HBIT)) == 0) {                                          \
                const int rB = r ^ (MR);                                      \
                const bool pos = (__builtin_popcount(r & (RR)) & 1) == 0;     \
                const h2v a = z[r], b = z[rB];                                \
                z[r]  = pkh_fma_hi(pos ? CP : CN, b, pkh_mul_lo(CP, a));      \
                z[rB] = pkh_fma_hi(pos ? CN : CP, a, pkh_mul_lo(CP, b));      \
            }                                                                 \
        }                                                                     \
    }
    REGGATE(3, 24, 16, 16)
    REGGATE(4, 12, 8, 24)
    REGGATE(5, 6, 4, 28)
    REGGATE(6, 3, 2, 30)
#undef REGGATE

    // ---- probabilities via v_dot2_f32_f16, folded straight into the trees:
    //  uu[k] = p[k] + p[k+16] = dot2(z[k], dot2(z[k+16], 0))
    //  vv[k] = p[k] - p[k+16] = uu[k] - 2*p[k+16]   (one FMA, inline -2.0)
    float Pu[8], Mu[8], Mv[8];
#pragma unroll
    for (int j = 0; j < 8; ++j) {
        const int k = 2 * j;
        const float p2a = dot2(z[k + 16], 0.0f);
        const float uua = dot2(z[k], p2a);
        const float vva = fmaf(-2.0f, p2a, uua);
        const float p2b = dot2(z[k + 17], 0.0f);
        const float uub = dot2(z[k + 1], p2b);
        const float vvb = fmaf(-2.0f, p2b, uub);
        Pu[j] = uua + uub;
        Mu[j] = uua - uub;
        Mv[j] = vva - vvb;
    }
    // ---- round-3/10-verified shared trees ----
    float PA[4], MB[4], Pv[4], Qv[4];
#pragma unroll
    for (int i = 0; i < 4; ++i) {
        PA[i] = Pu[2 * i] - Pu[2 * i + 1];
        MB[i] = Mu[2 * i] - Mu[2 * i + 1];
        Pv[i] = Mv[2 * i] + Mv[2 * i + 1];
        Qv[i] = Mv[2 * i] - Mv[2 * i + 1];
    }
    const float QA0 = PA[0] + PA[1], QA1 = PA[2] + PA[3];
    const float QB0 = MB[0] + MB[1], QB1 = MB[2] + MB[3];
    const float QF0 = MB[0] - MB[1], QF1 = MB[2] - MB[3];
    const float Pp0 = Pv[0] - Pv[1], Pp1 = Pv[2] - Pv[3];
    const float Qp0 = Qv[0] - Qv[1], Qp1 = Qv[2] - Qv[3];
    const float s0A = QA0 - QA1;
    const float s0B = QB0 - QB1;
    const float s0F = QF0 - QF1;
    const float s15 = Pp0 + Pp1;
    const float s17 = Qp0 + Qp1;
    const float s1F = Qp0 - Qp1;

    const float A  = p01 ? -1.f : 1.f;
    const float Bs = (__popc(L & 7) & 1) ? -1.f : 1.f;
    const float D  = (L & 2) ? -1.f : 1.f;
    float acc[8];
    acc[0] = A * s15;
    acc[1] = Bs * s1F;
    acc[2] = D * s1F;
    acc[3] = Bs * s0F;
    acc[4] = D * s17;
    acc[5] = Bs * s0B;
    acc[6] = D * s15;
    acc[7] = Bs * s0A;

    // ---- transpose-reduce over 8 lanes (DPP); lane L ends with sum of acc[L] ----
    const int h0 = L & 1, h1 = (L >> 1) & 1, h2 = (L >> 2) & 1;
    float t4a[4];
#pragma unroll
    for (int k = 0; k < 4; ++k) {
        const float send = h0 ? acc[2 * k] : acc[2 * k + 1];
        const float recv = dppf<DPP_XOR1>(send);
        t4a[k] = (h0 ? acc[2 * k + 1] : acc[2 * k]) + recv;
    }
    float t2a[2];
#pragma unroll
    for (int k = 0; k < 2; ++k) {
        const float send = h1 ? t4a[2 * k] : t4a[2 * k + 1];
        const float recv = dppf<DPP_XOR2>(send);
        t2a[k] = (h1 ? t4a[2 * k + 1] : t4a[2 * k]) + recv;
    }
    {
        const float send = h2 ? t2a[0] : t2a[1];
        const float recv = xor4f(send);
        const float res = (h2 ? t2a[1] : t2a[0]) + recv;
        out[(size_t)sample * 8 + L] = res;
    }
}

extern "C" void kernel_launch(void* const* d_in, const int* in_sizes, int n_in,
                              void* d_out, int out_size, void* d_ws, size_t ws_size,
                              hipStream_t stream) {
    const float* x = (const float*)d_in[0];
    const float* w = (const float*)d_in[1];
    float* outp = (float*)d_out;
    const int nsamples = in_sizes[0] / 8;
    const int nthreads = nsamples * 8;
    const int block = 256;
    const int grid = (nthreads + block - 1) / block;
    qsim8_kernel<<<grid, block, 0, stream>>>(x, w, outp, nsamples);
}

// Round 12
// 9.876 us; speedup vs baseline: 2.7004x; 2.0106x over previous
//
#include <hip/hip_runtime.h>

#define PI_OVER_2 1.57079632679489661923f

// Pauli/Heisenberg evaluation. Derivation anchored to round-1..10-VERIFIED masks:
//   ring map rows R_j (t-masks): R_0={1..7}, R_j={0..j} (j>=1)   [round-1 V list]
//   flip axes M_j = ring^-1(e_j): M_j={j,j+1} (j<=6), M_7={0,1,7} [round-2 gates]
// out_i = <phi| prod_{q in S_i} (C_q Z^{R_q} - S_q X^{M_q}) |phi>,  S_i = R_i-as-set,
// phi = layer-1 product state with Bloch (x,y,z) per qubit; C,S = cos/sin of the
// fused layer-2 RY FULL angle. Expansion term (choices d_q=1 -> X):
//   coeff = prod(-S_q; d=1) * prod(C_q; d=0)
//   mX_0 = d0^d7, mX_1 = d0^d1^d7, mX_j = d_{j-1}^d_j (j>=2)
//   mZ_0 = par(zeta_1..7), mZ_j = zeta_0 ^ par(zeta_j..7) (j>=1), zeta = 1-d on S
//   per-qubit <X^a Z^b>: (0,0)->1 (0,1)->z (1,0)->x (1,1)-> -i*y
// Summed by an unrolled DP sweeping q = QMAX..QMIN, state bits:
//   b0 = delta_q (prev choice), b1 = suffix zeta-parity, b2 = gamma hyp (=zeta_0,
//   validated at closure), b3 = delta_top (=d_QMAX, kept only when QMAX==7 for the
//   M_7 wraparound). Complex values carry the -i bookkeeping exactly.
// Hand-verified: all 4 terms of out_1; all-Z terms of out_1 (mask 0xBF) and
// out_2 (mask 0x5F) vs independent mask algebra.

struct Bloch {
    float zB[8], xB[8], yB[8], C[8], S[8];
};

template <int QMIN, int QMAX>
__device__ __forceinline__ float dp_eval(const Bloch& B) {
    float re[16], im[16];
#pragma unroll
    for (int i = 0; i < 16; ++i) { re[i] = 0.f; im[i] = 0.f; }

    // qubits above QMAX+1: factor z_j when gamma=1 (Z_0 spreads via R_0), else 1
    float zt = 1.f;
#pragma unroll
    for (int j = QMAX + 2; j < 8; ++j) zt *= B.zB[j];

    // ---- init: choose d_QMAX; emit factor for qubit QMAX+1 (if it exists) ----
#pragma unroll
    for (int gh = 0; gh < ((QMIN == 0) ? 2 : 1); ++gh) {
#pragma unroll
        for (int dl = 0; dl < 2; ++dl) {
            float v = dl ? -B.S[QMAX] : B.C[QMAX];
            if (gh) v *= zt;
            bool isY = false;
            if (QMAX < 7) {   // g(mX=dl, mZ=gh) on qubit QMAX+1
                if (!dl && gh)      v *= B.zB[QMAX + 1];
                else if (dl && !gh) v *= B.xB[QMAX + 1];
                else if (dl && gh) { v *= B.yB[QMAX + 1]; isY = true; }
            }
            const int dt = (QMAX == 7) ? dl : 0;
            const int idx = dl | ((1 - dl) << 1) | (gh << 2) | (dt << 3);
            if (isY) im[idx] -= v; else re[idx] += v;   // *(-i)
        }
    }

    // ---- sweep q = QMAX-1 .. QMIN; step q emits factor for qubit q+1 ----
#pragma unroll
    for (int q = QMAX - 1; q >= QMIN; --q) {
        float nre[16], nim[16];
#pragma unroll
        for (int i = 0; i < 16; ++i) { nre[i] = 0.f; nim[i] = 0.f; }
#pragma unroll
        for (int st = 0; st < 16; ++st) {
            const int dp_ = st & 1, s1 = (st >> 1) & 1;
            const int g_ = (st >> 2) & 1, dt = (st >> 3) & 1;
            if (QMIN == 1 && g_) continue;     // gamma fixed 0 (qubit 0 not in S)
            if (QMAX < 7 && dt) continue;      // no wraparound bit
#pragma unroll
            for (int dl = 0; dl < 2; ++dl) {
                const int mx = dl ^ dp_ ^ ((q == 0) ? dt : 0);  // mX_1 adds d7
                const int mz = g_ ^ s1;
                float F = dl ? -B.S[q] : B.C[q];
                bool isY = false;
                if (!mx && mz)      F *= B.zB[q + 1];
                else if (mx && !mz) F *= B.xB[q + 1];
                else if (mx && mz) { F *= B.yB[q + 1]; isY = true; }
                const int ns = dl | ((s1 ^ 1 ^ dl) << 1) | (g_ << 2) | (dt << 3);
                if (isY) {  // val *= -i*F
                    nre[ns] = fmaf(F, im[st], nre[ns]);
                    nim[ns] = fmaf(-F, re[st], nim[ns]);
                } else {
                    nre[ns] = fmaf(F, re[st], nre[ns]);
                    nim[ns] = fmaf(F, im[st], nim[ns]);
                }
            }
        }
#pragma unroll
        for (int i = 0; i < 16; ++i) { re[i] = nre[i]; im[i] = nim[i]; }
    }

    // ---- closure: gamma consistency + deferred qubit-0 (and qubit-1 for QMIN=1) ----
    float acc = 0.f;
#pragma unroll
    for (int st = 0; st < 16; ++st) {
        const int dp_ = st & 1, sf = (st >> 1) & 1;
        const int g_ = (st >> 2) & 1, dt = (st >> 3) & 1;
        if (QMIN == 1 && g_) continue;
        if (QMAX < 7 && dt) continue;
        if (QMIN == 0 && g_ != (1 - dp_)) continue;   // gamma = zeta_0 = 1-d0
        float r = re[st], i = im[st];
#define APPLYG(MX, MZ, J)                                                     \
        if ((MX) == 0 && (MZ) == 1) { r *= B.zB[J]; i *= B.zB[J]; }           \
        else if ((MX) == 1 && (MZ) == 0) { r *= B.xB[J]; i *= B.xB[J]; }      \
        else if ((MX) == 1 && (MZ) == 1) {                                    \
            const float t = r; r = i * B.yB[J]; i = -t * B.yB[J]; }
        {
            const int mx0 = (QMIN == 0) ? (dp_ ^ dt) : dt;
            const int mz0 = (QMIN == 0) ? (sf ^ g_) : sf;
            APPLYG(mx0, mz0, 0)
        }
        if (QMIN == 1) {   // factor_1 never emitted in-loop (loop ends at q=1)
            const int mx1 = dp_ ^ dt;
            const int mz1 = sf;
            APPLYG(mx1, mz1, 1)
        }
#undef APPLYG
        acc += r;
    }
    return acc;
}

__global__ __launch_bounds__(256) void qpauli_kernel(
        const float* __restrict__ x, const float* __restrict__ w,
        float* __restrict__ out, int nsamples) {
    const int gid = blockIdx.x * blockDim.x + threadIdx.x;
    const int wave = gid >> 6, lane = gid & 63;
    const int which = wave & 1;                 // wave-uniform: no divergence
    const int sample = (wave >> 1) * 64 + lane;
    if (sample >= nsamples) return;

    // ---- Bloch vectors (layer 1, FULL angles) + layer-2 coefficients ----
    Bloch B;
    const float4* xv = reinterpret_cast<const float4*>(x + (size_t)sample * 8);
    const float4 xa = xv[0], xb = xv[1];
    const float xs[8] = {xa.x, xa.y, xa.z, xa.w, xb.x, xb.y, xb.z, xb.w};
#pragma unroll
    for (int q = 0; q < 8; ++q) {
        const float A1 = fmaf(xs[q], PI_OVER_2, w[2 * q]);       // ry1 full
        const float W  = w[2 * q + 1];                           // rz1 full
        const float A2 = fmaf(xs[q], PI_OVER_2, w[16 + 2 * q]);  // ry2 full
        float s1, c1, sw, cw;
        __sincosf(A1, &s1, &c1);
        __sincosf(W, &sw, &cw);
        __sincosf(A2, &B.S[q], &B.C[q]);
        B.zB[q] = c1;
        B.xB[q] = s1 * cw;
        B.yB[q] = s1 * sw;
    }

    float* o = out + (size_t)sample * 8;
    if (which == 0) {
        o[7] = dp_eval<0, 7>(B);
        o[1] = dp_eval<0, 1>(B);
        o[2] = dp_eval<0, 2>(B);
        o[4] = dp_eval<0, 4>(B);
    } else {
        o[0] = dp_eval<1, 7>(B);
        o[3] = dp_eval<0, 3>(B);
        o[5] = dp_eval<0, 5>(B);
        o[6] = dp_eval<0, 6>(B);
    }
}

extern "C" void kernel_launch(void* const* d_in, const int* in_sizes, int n_in,
                              void* d_out, int out_size, void* d_ws, size_t ws_size,
                              hipStream_t stream) {
    const float* x = (const float*)d_in[0];
    const float* w = (const float*)d_in[1];
    float* outp = (float*)d_out;
    const int nsamples = in_sizes[0] / 8;
    const int nthreads = nsamples * 2;
    const int block = 256;
    const int grid = (nthreads + block - 1) / block;
    qpauli_kernel<<<grid, block, 0, stream>>>(x, w, outp, nsamples);
}